// Round 1
// baseline (492.439 us; speedup 1.0000x reference)
//
#include <hip/hip_runtime.h>

#define B_SZ 32
#define LK   4096
#define H    512
#define MT   64           // key rows per block
#define AST  1040         // A-LDS byte stride per k8: 64*16 + 16 pad (quads land on distinct banks)

typedef __bf16 bf16x8 __attribute__((ext_vector_type(8)));
typedef float  f32x4  __attribute__((ext_vector_type(4)));

__device__ inline unsigned short f2bf_rne(float f) {
    unsigned int u = __float_as_uint(f);
    u += 0x7FFFu + ((u >> 16) & 1u);
    return (unsigned short)(u >> 16);
}
__device__ inline unsigned pack_trunc(float lo, float hi) {
    return __builtin_amdgcn_perm(__float_as_uint(hi), __float_as_uint(lo), 0x07060302u);
}
__device__ inline float tanh_fast(float x) {
    float e = __expf(2.0f * x);
    return 1.0f - 2.0f * __builtin_amdgcn_rcpf(e + 1.0f);
}

// ---- kernel 1: Ua_w fp32 [n][k] -> bf16 k-major tiles ua_t[k8][n][8] ----
__global__ void cvt_ua_kernel(const float* __restrict__ Ua_w, unsigned short* __restrict__ ua_t) {
    int n = blockIdx.x;          // 512 blocks
    int t = threadIdx.x;         // 256 threads, each 2 k's
    float2 f = *(const float2*)(Ua_w + n * H + t * 2);
    unsigned w = (unsigned)f2bf_rne(f.x) | ((unsigned)f2bf_rne(f.y) << 16);
    int k8 = t >> 2, off = t & 3;
    *(unsigned*)(ua_t + (size_t)k8 * (H * 8) + n * 8 + off * 2) = w;
}

// ---- kernel 2: qadd[b][n] = query[b] . Wa_w[n] + Wa_b[n] + Ua_b[n] ----
__global__ void qproj_kernel(const float* __restrict__ query, const float* __restrict__ Wa_w,
                             const float* __restrict__ Wa_b, const float* __restrict__ Ua_b,
                             float* __restrict__ qadd) {
    __shared__ float qs[H];
    int b = blockIdx.x >> 3;
    int hseg = (blockIdx.x & 7) * 64;
    int t = threadIdx.x, wave = t >> 6, lane = t & 63;
    qs[t] = query[b * H + t];
    qs[t + 256] = query[b * H + t + 256];
    __syncthreads();
    for (int i = 0; i < 16; ++i) {
        int h = hseg + wave * 16 + i;
        const float* wr = Wa_w + (size_t)h * H + lane * 8;
        float4 a = *(const float4*)wr;
        float4 c = *(const float4*)(wr + 4);
        const float* q8 = qs + lane * 8;
        float s = a.x * q8[0] + a.y * q8[1] + a.z * q8[2] + a.w * q8[3]
                + c.x * q8[4] + c.y * q8[5] + c.z * q8[6] + c.w * q8[7];
        s += __shfl_xor(s, 1);  s += __shfl_xor(s, 2);  s += __shfl_xor(s, 4);
        s += __shfl_xor(s, 8);  s += __shfl_xor(s, 16); s += __shfl_xor(s, 32);
        if (lane == 0) qadd[b * H + h] = s + Wa_b[h] + Ua_b[h];
    }
}

// ---- kernel 3: main fused kernel ----
// grid 2048 = 32 b x 64 row-tiles of 64; 512 threads (8 waves = 2M x 4N)
// A (keys tile) bf16 full-K in LDS, staged per-K-chunk with issue-early/pack-late;
// B (ua_t) double-buffered via global_load_lds (32 KB chunks). One barrier per kc.
__global__ __launch_bounds__(512, 2)
void main_kernel(const float* __restrict__ keys, const unsigned short* __restrict__ ua_t,
                 const float* __restrict__ qadd, const float* __restrict__ va_w,
                 const float* __restrict__ va_b, const float* __restrict__ temp,
                 const int* __restrict__ valid, float* __restrict__ p_out,
                 float* __restrict__ pc_part, float* __restrict__ psum_part) {
    __shared__ __align__(16) unsigned char alds[64 * AST];     // 66560 B
    __shared__ __align__(16) unsigned char blds[2][32768];     // 65536 B (dbuf; reused as red)
    __shared__ float swave[8][32];
    __shared__ float pbuf[MT];

    const int blk  = blockIdx.x;
    const int b    = blk >> 6;
    const int m0   = (blk & 63) * MT;
    const int t    = threadIdx.x;
    const int wave = t >> 6;
    const int lane = t & 63;
    const int lrow = lane & 15;
    const int lquad = lane >> 4;
    const int wm   = wave >> 2;   // 0..1  (M half)
    const int wn   = wave & 3;    // 0..3  (N quarter)

    const float* keys_b = keys + ((size_t)b * LK + m0) * H;

    // async B-chunk stage: 32 KB contiguous slab of ua_t -> blds[buf] (linear)
    auto issueB = [&](int kc, int buf) {
        const unsigned short* slab = ua_t + (size_t)kc * (4 * 512 * 8);
        #pragma unroll
        for (int it = 0; it < 4; ++it) {
            int i = it * 512 + t;                  // 0..2047, 16 B each
            __builtin_amdgcn_global_load_lds(
                (const __attribute__((address_space(1))) void*)(slab + (size_t)i * 8),
                (__attribute__((address_space(3))) void*)(blds[buf] + i * 16),
                16, 0, 0);
        }
    };

    // A staging mapping: thread -> (row, k-quad, half). 8 consecutive threads
    // cover one row's 128 B k-window contiguously (coalesced).
    const int sh   = t & 1;          // which float4 half of the octet
    const int sq   = (t >> 1) & 3;   // k-quad within chunk
    const int srow = t >> 3;         // 0..63
    const float* a_src = keys_b + (size_t)srow * H + sq * 8 + sh * 4;
    unsigned char* a_dst = alds + sq * AST + srow * 16 + sh * 8;

    // ---- prologue: A(0) loads, B(0) issue, A(0) pack/write ----
    float4 fa = *(const float4*)a_src;
    issueB(0, 0);
    {
        uint2 w;
        w.x = pack_trunc(fa.x, fa.y);
        w.y = pack_trunc(fa.z, fa.w);
        *(uint2*)a_dst = w;
    }

    float va[8], qa[8];
    #pragma unroll
    for (int nt = 0; nt < 8; ++nt) {
        int n = wn * 128 + nt * 16 + lrow;
        va[nt] = va_w[n];
        qa[nt] = qadd[b * H + n];
    }

    f32x4 acc[2][8];
    #pragma unroll
    for (int mt = 0; mt < 2; ++mt)
        #pragma unroll
        for (int nt = 0; nt < 8; ++nt)
            acc[mt][nt] = (f32x4){0.f, 0.f, 0.f, 0.f};

    __syncthreads();   // A(0) written + B(0) arrived (vmcnt drain at barrier)

    // ---- K-loop: 16 chunks of 32 k, one barrier per chunk ----
    for (int kc = 0; kc < 16; ++kc) {
        float4 fnext;
        if (kc < 15) {
            // issue-early: next A chunk to regs (HBM latency hides under MFMAs)
            fnext = *(const float4*)(a_src + (kc + 1) * 32);
            // async: next B chunk into the other buffer (read of it finished at kc-1 barrier)
            issueB(kc + 1, (kc + 1) & 1);
        }

        bf16x8 af[2];
        #pragma unroll
        for (int mt = 0; mt < 2; ++mt)
            af[mt] = *(const bf16x8*)(alds + (kc * 4 + lquad) * AST + (wm * 32 + mt * 16 + lrow) * 16);
        const unsigned char* bbase = blds[kc & 1];
        #pragma unroll
        for (int nt = 0; nt < 8; ++nt) {
            int n = wn * 128 + nt * 16 + lrow;
            bf16x8 bfrag = *(const bf16x8*)(bbase + (lquad * 512 + n) * 16);
            acc[0][nt] = __builtin_amdgcn_mfma_f32_16x16x32_bf16(af[0], bfrag, acc[0][nt], 0, 0, 0);
            acc[1][nt] = __builtin_amdgcn_mfma_f32_16x16x32_bf16(af[1], bfrag, acc[1][nt], 0, 0, 0);
        }

        if (kc < 15) {
            // write-late: pack next A chunk into its (fresh) LDS slot
            uint2 w;
            w.x = pack_trunc(fnext.x, fnext.y);
            w.y = pack_trunc(fnext.z, fnext.w);
            *(uint2*)(a_dst + (size_t)(kc + 1) * 4 * AST) = w;
        }
        __syncthreads();   // drains B(kc+1) vmcnt + A(kc+1) lgkm; cost ~ max(0, load-compute)
    }

    // ---- score: per row, sum_n tanh(kproj + qadd) * va, reduce over n ----
    #pragma unroll
    for (int mt = 0; mt < 2; ++mt) {
        #pragma unroll
        for (int r = 0; r < 4; ++r) {
            float s = 0.f;
            #pragma unroll
            for (int nt = 0; nt < 8; ++nt)
                s += tanh_fast(acc[mt][nt][r] + qa[nt]) * va[nt];
            s += __shfl_xor(s, 1); s += __shfl_xor(s, 2);
            s += __shfl_xor(s, 4); s += __shfl_xor(s, 8);
            if (lrow == 0) swave[wave][mt * 16 + lquad * 4 + r] = s;
        }
    }
    __syncthreads();

    // ---- p = exp(score/T) masked; per-block psum partial ----
    if (t < MT) {
        int wmt = t >> 5, idx = t & 31;
        float score = (swave[wmt * 4 + 0][idx] + swave[wmt * 4 + 1][idx]
                     + swave[wmt * 4 + 2][idx] + swave[wmt * 4 + 3][idx] + va_b[0]) / temp[0];
        int l = m0 + t;
        float p = (l < valid[b]) ? __expf(score) : 0.f;
        p_out[(size_t)b * LK + l] = p;
        pbuf[t] = p;
        float s = p;
        s += __shfl_xor(s, 1);  s += __shfl_xor(s, 2);  s += __shfl_xor(s, 4);
        s += __shfl_xor(s, 8);  s += __shfl_xor(s, 16); s += __shfl_xor(s, 32);
        if (t == 0) psum_part[blk] = s;
    }
    __syncthreads();

    // ---- partial context: pc_part[blk][h] = sum_row p[row]*key_bf[row][h] ----
    {
        float* red = (float*)blds;         // overlay B buffer (16 KB used)
        int oct = t & 63, rg = t >> 6;     // k-octet x row-group of 8
        float s8[8];
        #pragma unroll
        for (int j = 0; j < 8; ++j) s8[j] = 0.f;
        #pragma unroll
        for (int rr = 0; rr < 8; ++rr) {
            int row = rg * 8 + rr;
            bf16x8 kv = *(const bf16x8*)(alds + oct * AST + row * 16);
            float pr = pbuf[row];
            #pragma unroll
            for (int j = 0; j < 8; ++j)
                s8[j] += pr * (float)kv[j];
        }
        #pragma unroll
        for (int j = 0; j < 8; ++j)
            red[rg * H + oct * 8 + j] = s8[j];
    }
    __syncthreads();
    {
        const float* red = (const float*)blds;
        float s = 0.f;
        #pragma unroll
        for (int rg = 0; rg < 8; ++rg)
            s += red[rg * H + t];
        pc_part[(size_t)blk * H + t] = s;
    }
}

// ---- kernel 4: finalize ----
__global__ void finalize_kernel(const float* __restrict__ p, const float* __restrict__ pc_part,
                                const float* __restrict__ psum_part, float* __restrict__ out) {
    int b = blockIdx.x / 18;
    int seg = blockIdx.x % 18;
    int t = threadIdx.x;
    __shared__ float tmp;
    if (t < 64) {
        float v = psum_part[b * 64 + t];
        v += __shfl_xor(v, 1);  v += __shfl_xor(v, 2);  v += __shfl_xor(v, 4);
        v += __shfl_xor(v, 8);  v += __shfl_xor(v, 16); v += __shfl_xor(v, 32);
        if (t == 0) tmp = v;
    }
    __syncthreads();
    float inv = 1.0f / tmp;
    if (seg < 16) {
        int l = seg * 256 + t;
        out[B_SZ * H + (size_t)b * LK + l] = p[(size_t)b * LK + l] * inv;
    } else {
        int h = (seg - 16) * 256 + t;
        float s = 0.f;
        #pragma unroll 8
        for (int i = 0; i < 64; ++i)
            s += pc_part[((size_t)b * 64 + i) * H + h];
        out[b * H + h] = s * inv;
    }
}

extern "C" void kernel_launch(void* const* d_in, const int* in_sizes, int n_in,
                              void* d_out, int out_size, void* d_ws, size_t ws_size,
                              hipStream_t stream) {
    const float* query = (const float*)d_in[0];
    const float* keys  = (const float*)d_in[1];
    const float* Wa_w  = (const float*)d_in[2];
    const float* Wa_b  = (const float*)d_in[3];
    const float* Ua_w  = (const float*)d_in[4];
    const float* Ua_b  = (const float*)d_in[5];
    const float* Va_w  = (const float*)d_in[6];
    const float* Va_b  = (const float*)d_in[7];
    const float* temp  = (const float*)d_in[8];
    const int*   valid = (const int*)d_in[9];
    float* out = (float*)d_out;

    char* ws = (char*)d_ws;
    unsigned short* ua_t = (unsigned short*)ws;            //   524288 B
    float* qadd      = (float*)(ws + 524288);              //    65536 B
    float* p         = (float*)(ws + 589824);              //   524288 B
    float* psum_part = (float*)(ws + 1114112);             //     8192 B
    float* pc_part   = (float*)(ws + 1122304);             //  4194304 B

    cvt_ua_kernel<<<H, 256, 0, stream>>>(Ua_w, ua_t);
    qproj_kernel<<<B_SZ * 8, 256, 0, stream>>>(query, Wa_w, Wa_b, Ua_b, qadd);
    main_kernel<<<B_SZ * (LK / MT), 512, 0, stream>>>(keys, ua_t, qadd, Va_w, Va_b,
                                                      temp, valid, p, pc_part, psum_part);
    finalize_kernel<<<B_SZ * 18, 256, 0, stream>>>(p, pc_part, psum_part, out);
}

// Round 2
// 459.059 us; speedup vs baseline: 1.0727x; 1.0727x over previous
//
#include <hip/hip_runtime.h>

#define B_SZ 32
#define LK   4096
#define H    512
#define MT   64           // key rows per block

typedef __bf16 bf16x8 __attribute__((ext_vector_type(8)));
typedef float  f32x4  __attribute__((ext_vector_type(4)));

__device__ inline unsigned short f2bf_rne(float f) {
    unsigned int u = __float_as_uint(f);
    u += 0x7FFFu + ((u >> 16) & 1u);
    return (unsigned short)(u >> 16);
}
__device__ inline unsigned pack_trunc(float lo, float hi) {
    return __builtin_amdgcn_perm(__float_as_uint(hi), __float_as_uint(lo), 0x07060302u);
}
__device__ inline float tanh_fast(float x) {
    float e = __expf(2.0f * x);
    return 1.0f - 2.0f * __builtin_amdgcn_rcpf(e + 1.0f);
}

// ---- kernel 1: Ua_w fp32 [n][k] -> bf16 k-major tiles ua_t[k8][n][8] ----
__global__ void cvt_ua_kernel(const float* __restrict__ Ua_w, unsigned short* __restrict__ ua_t) {
    int n = blockIdx.x;          // 512 blocks
    int t = threadIdx.x;         // 256 threads, each 2 k's
    float2 f = *(const float2*)(Ua_w + n * H + t * 2);
    unsigned w = (unsigned)f2bf_rne(f.x) | ((unsigned)f2bf_rne(f.y) << 16);
    int k8 = t >> 2, off = t & 3;
    *(unsigned*)(ua_t + (size_t)k8 * (H * 8) + n * 8 + off * 2) = w;
}

// ---- kernel 2: qadd[b][n] = query[b] . Wa_w[n] + Wa_b[n] + Ua_b[n] ----
__global__ void qproj_kernel(const float* __restrict__ query, const float* __restrict__ Wa_w,
                             const float* __restrict__ Wa_b, const float* __restrict__ Ua_b,
                             float* __restrict__ qadd) {
    __shared__ float qs[H];
    int b = blockIdx.x >> 3;
    int hseg = (blockIdx.x & 7) * 64;
    int t = threadIdx.x, wave = t >> 6, lane = t & 63;
    qs[t] = query[b * H + t];
    qs[t + 256] = query[b * H + t + 256];
    __syncthreads();
    for (int i = 0; i < 16; ++i) {
        int h = hseg + wave * 16 + i;
        const float* wr = Wa_w + (size_t)h * H + lane * 8;
        float4 a = *(const float4*)wr;
        float4 c = *(const float4*)(wr + 4);
        const float* q8 = qs + lane * 8;
        float s = a.x * q8[0] + a.y * q8[1] + a.z * q8[2] + a.w * q8[3]
                + c.x * q8[4] + c.y * q8[5] + c.z * q8[6] + c.w * q8[7];
        s += __shfl_xor(s, 1);  s += __shfl_xor(s, 2);  s += __shfl_xor(s, 4);
        s += __shfl_xor(s, 8);  s += __shfl_xor(s, 16); s += __shfl_xor(s, 32);
        if (lane == 0) qadd[b * H + h] = s + Wa_b[h] + Ua_b[h];
    }
}

// ---- kernel 3: main fused kernel ----
// grid 2048 = 32 b x 64 row-tiles of 64; 512 threads (8 waves = 2M x 4N)
// Counted-vmcnt pipeline: B (ua_t) 3-buffered via global_load_lds, chunk j+2
// issued during j; A (keys) 3-deep asm register prefetch, chunk j+3 issued at
// j, packed/ds_written at j. One raw s_barrier per chunk; vmcnt never drains
// to 0 in the steady-state loop. LDS = exactly 160 KiB.
__global__ __launch_bounds__(512, 2)
void main_kernel(const float* __restrict__ keys, const unsigned short* __restrict__ ua_t,
                 const float* __restrict__ qadd, const float* __restrict__ va_w,
                 const float* __restrict__ va_b, const float* __restrict__ temp,
                 const int* __restrict__ valid, float* __restrict__ p_out,
                 float* __restrict__ pc_part, float* __restrict__ psum_part) {
    // carve: alds 64 KB (A, XOR-swizzled) | blds 3 x 32 KB (B triple buffer)
    // epilogue overlays live inside buf0 (dead after K-loop + final barrier)
    __shared__ __align__(16) unsigned char lds[163840];
    unsigned char* alds = lds;
    unsigned char* blds = lds + 65536;
    float* red   = (float*)(lds + 65536);           // 16 KB
    float* swave = (float*)(lds + 65536 + 16384);   // 1 KB  [8][32]
    float* pbuf  = (float*)(lds + 65536 + 17408);   // 256 B [64]

    const int blk  = blockIdx.x;
    const int b    = blk >> 6;
    const int m0   = (blk & 63) * MT;
    const int t    = threadIdx.x;
    const int wave = t >> 6;
    const int lane = t & 63;
    const int lrow = lane & 15;
    const int lquad = lane >> 4;
    const int wm   = wave >> 2;   // 0..1  (M half)
    const int wn   = wave & 3;    // 0..3  (N quarter)

    const float* keys_b = keys + ((size_t)b * LK + m0) * H;

    // async B-chunk stage: 32 KB contiguous slab of ua_t -> blds buf (linear)
    auto issueB = [&](int kc, int buf) {
        const unsigned short* slab = ua_t + (size_t)kc * (4 * 512 * 8);
        unsigned char* dst = blds + buf * 32768;
        #pragma unroll
        for (int it = 0; it < 4; ++it) {
            int i = it * 512 + t;                  // 0..2047, 16 B each
            __builtin_amdgcn_global_load_lds(
                (const __attribute__((address_space(1))) void*)(slab + (size_t)i * 8),
                (__attribute__((address_space(3))) void*)(dst + i * 16),
                16, 0, 0);
        }
    };

    // A staging mapping: thread -> (row, k-quad, half); 8 consecutive threads
    // cover one row's 128 B k-window contiguously (coalesced HBM).
    const int sh   = t & 1;
    const int sq   = (t >> 1) & 3;
    const int srow = t >> 3;
    const float* a_src = keys_b + (size_t)srow * H + sq * 8 + sh * 4;

    // A LDS XOR swizzle: byte(k8,row) = k8*1024 + ((row*16) ^ ((k8&7)<<4))
    auto packA = [&](int c, f32x4 f) {
        uint2 w;
        w.x = pack_trunc(f[0], f[1]);
        w.y = pack_trunc(f[2], f[3]);
        int k8 = c * 4 + sq;
        *(uint2*)(alds + k8 * 1024 + ((srow * 16) ^ ((k8 & 7) << 4)) + sh * 8) = w;
    };

    // ---- prologue: all compiler-visible VMEM first, then full drain ----
    float va[8], qa[8];
    #pragma unroll
    for (int nt = 0; nt < 8; ++nt) {
        int n = wn * 128 + nt * 16 + lrow;
        va[nt] = va_w[n];
        qa[nt] = qadd[b * H + n];
    }
    const int   valid_b = valid[b];
    const float tv      = temp[0];
    const float vab     = va_b[0];
    asm volatile("s_waitcnt vmcnt(0) lgkmcnt(0)" ::: "memory");
    __builtin_amdgcn_sched_barrier(0);

    // pipeline fill: A0,A1,B0,A2,B1  (queue: A0 A1 B0x4 A2 B1x4 = 11)
    f32x4 fa[3];
    asm volatile("global_load_dwordx4 %0, %1, off" : "=v"(fa[0]) : "v"(a_src));
    asm volatile("global_load_dwordx4 %0, %1, off" : "=v"(fa[1]) : "v"(a_src + 32));
    issueB(0, 0);
    asm volatile("global_load_dwordx4 %0, %1, off" : "=v"(fa[2]) : "v"(a_src + 64));
    issueB(1, 1);

    f32x4 acc[2][8];
    #pragma unroll
    for (int mt = 0; mt < 2; ++mt)
        #pragma unroll
        for (int nt = 0; nt < 8; ++nt)
            acc[mt][nt] = (f32x4){0.f, 0.f, 0.f, 0.f};

    asm volatile("s_waitcnt vmcnt(10)" ::: "memory");   // A0 done
    __builtin_amdgcn_sched_barrier(0);
    packA(0, fa[0]);
    asm volatile("s_waitcnt vmcnt(5)" ::: "memory");    // A1,B0 done; [A2,B1x4] left
    asm volatile("s_waitcnt lgkmcnt(0)" ::: "memory");
    __builtin_amdgcn_sched_barrier(0);
    __builtin_amdgcn_s_barrier();

    // ---- K-loop: 16 chunks of 32 k; steady queue [A(j+2), B(j+1)x4] on entry ----
    #pragma unroll
    for (int j = 0; j < 16; ++j) {
        if (j < 15) packA(j + 1, fa[(j + 1) % 3]);                  // retired last iter
        if (j <= 12)
            asm volatile("global_load_dwordx4 %0, %1, off"
                         : "=v"(fa[j % 3]) : "v"(a_src + (j + 3) * 32));
        if (j <= 13) issueB(j + 2, (j + 2) % 3);

        bf16x8 af[2];
        #pragma unroll
        for (int mt = 0; mt < 2; ++mt) {
            int k8 = j * 4 + lquad;
            int row16 = (wm * 32 + mt * 16 + lrow) * 16;
            af[mt] = *(const bf16x8*)(alds + k8 * 1024 + (row16 ^ ((k8 & 7) << 4)));
        }
        const unsigned char* bbase = blds + (j % 3) * 32768;
        __builtin_amdgcn_s_setprio(1);
        #pragma unroll
        for (int nt = 0; nt < 8; ++nt) {
            int n = wn * 128 + nt * 16 + lrow;
            bf16x8 bfrag = *(const bf16x8*)(bbase + (lquad * 512 + n) * 16);
            acc[0][nt] = __builtin_amdgcn_mfma_f32_16x16x32_bf16(af[0], bfrag, acc[0][nt], 0, 0, 0);
            acc[1][nt] = __builtin_amdgcn_mfma_f32_16x16x32_bf16(af[1], bfrag, acc[1][nt], 0, 0, 0);
        }
        __builtin_amdgcn_s_setprio(0);

        __builtin_amdgcn_sched_barrier(0);
        asm volatile("s_waitcnt lgkmcnt(0)" ::: "memory");           // A write + reads done
        if (j <= 12)      { asm volatile("s_waitcnt vmcnt(5)" ::: "memory"); }  // B(j+1),A(j+2) in
        else if (j == 13) { asm volatile("s_waitcnt vmcnt(4)" ::: "memory"); }  // B14,A15 in
        else              { asm volatile("s_waitcnt vmcnt(0)" ::: "memory"); }
        __builtin_amdgcn_sched_barrier(0);
        __builtin_amdgcn_s_barrier();
    }

    // ---- score: per row, sum_n tanh(kproj + qadd) * va, reduce over n ----
    #pragma unroll
    for (int mt = 0; mt < 2; ++mt) {
        #pragma unroll
        for (int r = 0; r < 4; ++r) {
            float s = 0.f;
            #pragma unroll
            for (int nt = 0; nt < 8; ++nt)
                s += tanh_fast(acc[mt][nt][r] + qa[nt]) * va[nt];
            s += __shfl_xor(s, 1); s += __shfl_xor(s, 2);
            s += __shfl_xor(s, 4); s += __shfl_xor(s, 8);
            if (lrow == 0) swave[wave * 32 + mt * 16 + lquad * 4 + r] = s;
        }
    }
    __syncthreads();

    // ---- p = exp(score/T) masked; per-block psum partial ----
    if (t < MT) {
        int wmt = t >> 5, idx = t & 31;
        float score = (swave[(wmt * 4 + 0) * 32 + idx] + swave[(wmt * 4 + 1) * 32 + idx]
                     + swave[(wmt * 4 + 2) * 32 + idx] + swave[(wmt * 4 + 3) * 32 + idx]
                     + vab) / tv;
        int l = m0 + t;
        float p = (l < valid_b) ? __expf(score) : 0.f;
        p_out[(size_t)b * LK + l] = p;
        pbuf[t] = p;
        float s = p;
        s += __shfl_xor(s, 1);  s += __shfl_xor(s, 2);  s += __shfl_xor(s, 4);
        s += __shfl_xor(s, 8);  s += __shfl_xor(s, 16); s += __shfl_xor(s, 32);
        if (t == 0) psum_part[blk] = s;
    }
    __syncthreads();

    // ---- partial context: pc_part[blk][h] = sum_row p[row]*key_bf[row][h] ----
    {
        int oct = t & 63, rg = t >> 6;     // k-octet x row-group of 8
        float s8[8];
        #pragma unroll
        for (int jj = 0; jj < 8; ++jj) s8[jj] = 0.f;
        #pragma unroll
        for (int rr = 0; rr < 8; ++rr) {
            int row = rg * 8 + rr;
            bf16x8 kv = *(const bf16x8*)(alds + oct * 1024 + ((row * 16) ^ ((oct & 7) << 4)));
            float pr = pbuf[row];
            #pragma unroll
            for (int jj = 0; jj < 8; ++jj)
                s8[jj] += pr * (float)kv[jj];
        }
        #pragma unroll
        for (int jj = 0; jj < 8; ++jj)
            red[rg * H + oct * 8 + jj] = s8[jj];
    }
    __syncthreads();
    {
        float s = 0.f;
        #pragma unroll
        for (int rg = 0; rg < 8; ++rg)
            s += red[rg * H + t];
        pc_part[(size_t)blk * H + t] = s;
    }
}

// ---- kernel 4: finalize ----
__global__ void finalize_kernel(const float* __restrict__ p, const float* __restrict__ pc_part,
                                const float* __restrict__ psum_part, float* __restrict__ out) {
    int b = blockIdx.x / 18;
    int seg = blockIdx.x % 18;
    int t = threadIdx.x;
    __shared__ float tmp;
    if (t < 64) {
        float v = psum_part[b * 64 + t];
        v += __shfl_xor(v, 1);  v += __shfl_xor(v, 2);  v += __shfl_xor(v, 4);
        v += __shfl_xor(v, 8);  v += __shfl_xor(v, 16); v += __shfl_xor(v, 32);
        if (t == 0) tmp = v;
    }
    __syncthreads();
    float inv = 1.0f / tmp;
    if (seg < 16) {
        int l = seg * 256 + t;
        out[B_SZ * H + (size_t)b * LK + l] = p[(size_t)b * LK + l] * inv;
    } else {
        int h = (seg - 16) * 256 + t;
        float s = 0.f;
        #pragma unroll 8
        for (int i = 0; i < 64; ++i)
            s += pc_part[((size_t)b * 64 + i) * H + h];
        out[b * H + h] = s * inv;
    }
}

extern "C" void kernel_launch(void* const* d_in, const int* in_sizes, int n_in,
                              void* d_out, int out_size, void* d_ws, size_t ws_size,
                              hipStream_t stream) {
    const float* query = (const float*)d_in[0];
    const float* keys  = (const float*)d_in[1];
    const float* Wa_w  = (const float*)d_in[2];
    const float* Wa_b  = (const float*)d_in[3];
    const float* Ua_w  = (const float*)d_in[4];
    const float* Ua_b  = (const float*)d_in[5];
    const float* Va_w  = (const float*)d_in[6];
    const float* Va_b  = (const float*)d_in[7];
    const float* temp  = (const float*)d_in[8];
    const int*   valid = (const int*)d_in[9];
    float* out = (float*)d_out;

    char* ws = (char*)d_ws;
    unsigned short* ua_t = (unsigned short*)ws;            //   524288 B
    float* qadd      = (float*)(ws + 524288);              //    65536 B
    float* p         = (float*)(ws + 589824);              //   524288 B
    float* psum_part = (float*)(ws + 1114112);             //     8192 B
    float* pc_part   = (float*)(ws + 1122304);             //  4194304 B

    cvt_ua_kernel<<<H, 256, 0, stream>>>(Ua_w, ua_t);
    qproj_kernel<<<B_SZ * 8, 256, 0, stream>>>(query, Wa_w, Wa_b, Ua_b, qadd);
    main_kernel<<<B_SZ * (LK / MT), 512, 0, stream>>>(keys, ua_t, qadd, Va_w, Va_b,
                                                      temp, valid, p, pc_part, psum_part);
    finalize_kernel<<<B_SZ * 18, 256, 0, stream>>>(p, pc_part, psum_part, out);
}

// Round 3
// 419.039 us; speedup vs baseline: 1.1752x; 1.0955x over previous
//
#include <hip/hip_runtime.h>

#define B_SZ 32
#define LK   4096
#define H    512
#define MT   64           // key rows per block

typedef __bf16 bf16x8 __attribute__((ext_vector_type(8)));
typedef float  f32x4  __attribute__((ext_vector_type(4)));

__device__ inline unsigned short f2bf_rne(float f) {
    unsigned int u = __float_as_uint(f);
    u += 0x7FFFu + ((u >> 16) & 1u);
    return (unsigned short)(u >> 16);
}
__device__ inline unsigned pack_trunc(float lo, float hi) {
    return __builtin_amdgcn_perm(__float_as_uint(hi), __float_as_uint(lo), 0x07060302u);
}
__device__ inline float tanh_fast(float x) {
    float e = __expf(2.0f * x);
    return 1.0f - 2.0f * __builtin_amdgcn_rcpf(e + 1.0f);
}
// A-tile LDS offset: slab per k8, XOR swizzle keeps af-reads / packA-writes /
// epilogue reads conflict-free (bits 4-6 from k8&7, bits 8-9 from k8&3)
__device__ inline int aoff(int k8, int row) {
    return k8 * 1024 + ((row * 16) ^ (((k8 & 7) << 4) | ((k8 & 3) << 8)));
}

// ---- kernel 1: Ua_w fp32 [n][k] -> bf16 k-major tiles ua_t[k8][n][8] ----
__global__ void cvt_ua_kernel(const float* __restrict__ Ua_w, unsigned short* __restrict__ ua_t) {
    int n = blockIdx.x;          // 512 blocks
    int t = threadIdx.x;         // 256 threads, each 2 k's
    float2 f = *(const float2*)(Ua_w + n * H + t * 2);
    unsigned w = (unsigned)f2bf_rne(f.x) | ((unsigned)f2bf_rne(f.y) << 16);
    int k8 = t >> 2, off = t & 3;
    *(unsigned*)(ua_t + (size_t)k8 * (H * 8) + n * 8 + off * 2) = w;
}

// ---- kernel 2: qadd[b][n] = query[b] . Wa_w[n] + Wa_b[n] + Ua_b[n] ----
__global__ void qproj_kernel(const float* __restrict__ query, const float* __restrict__ Wa_w,
                             const float* __restrict__ Wa_b, const float* __restrict__ Ua_b,
                             float* __restrict__ qadd) {
    __shared__ float qs[H];
    int b = blockIdx.x >> 3;
    int hseg = (blockIdx.x & 7) * 64;
    int t = threadIdx.x, wave = t >> 6, lane = t & 63;
    qs[t] = query[b * H + t];
    qs[t + 256] = query[b * H + t + 256];
    __syncthreads();
    for (int i = 0; i < 16; ++i) {
        int h = hseg + wave * 16 + i;
        const float* wr = Wa_w + (size_t)h * H + lane * 8;
        float4 a = *(const float4*)wr;
        float4 c = *(const float4*)(wr + 4);
        const float* q8 = qs + lane * 8;
        float s = a.x * q8[0] + a.y * q8[1] + a.z * q8[2] + a.w * q8[3]
                + c.x * q8[4] + c.y * q8[5] + c.z * q8[6] + c.w * q8[7];
        s += __shfl_xor(s, 1);  s += __shfl_xor(s, 2);  s += __shfl_xor(s, 4);
        s += __shfl_xor(s, 8);  s += __shfl_xor(s, 16); s += __shfl_xor(s, 32);
        if (lane == 0) qadd[b * H + h] = s + Wa_b[h] + Ua_b[h];
    }
}

// ---- kernel 3: main fused kernel ----
// grid 2048 = 32 b x 64 row-tiles of 64; 256 threads (4 waves, G_m=1 x G_n=4)
// Each wave: M=64 x N=128, acc[4][8] = 128 VGPR. B (ua_t) loaded DIRECTLY
// global->reg, double-buffered (compiler-counted vmcnt, never drained in-loop).
// A (keys) chunk-staged to a full-K 64 KB LDS tile (kept for context epilogue)
// via fa reg pipeline; one raw s_barrier + lgkmcnt(0) per chunk (A sync only).
// LDS 75 KB -> 2 independent blocks/CU cover each other's stalls.
__global__ __launch_bounds__(256, 2)
void main_kernel(const float* __restrict__ keys, const unsigned short* __restrict__ ua_t,
                 const float* __restrict__ qadd, const float* __restrict__ va_w,
                 const float* __restrict__ va_b, const float* __restrict__ temp,
                 const int* __restrict__ valid, float* __restrict__ p_out,
                 float* __restrict__ pc_part, float* __restrict__ psum_part) {
    __shared__ __align__(16) unsigned char alds[65536];   // A full-K bf16, swizzled
    __shared__ float red[4][H];                           // 8 KB epilogue scratch
    __shared__ float swave[4][MT];                        // 1 KB
    __shared__ float pbuf[MT];

    const int blk  = blockIdx.x;
    const int b    = blk >> 6;
    const int m0   = (blk & 63) * MT;
    const int t    = threadIdx.x;
    const int wave = t >> 6;      // 0..3 = n-quarter
    const int lane = t & 63;
    const int lrow = lane & 15;
    const int lquad = lane >> 4;

    const float* keys_b = keys + ((size_t)b * LK + m0) * H;

    // A staging: thread -> (srow = t>>2 in 0..63, sq = t&3); 8 floats/chunk -> 1 uint4
    const int sq = t & 3, srow = t >> 2;
    const float* a_src = keys_b + (size_t)srow * H + sq * 8;

    // B fragment base for this lane (elements): k8 = j*4+lquad, n = wave*128+nt*16+lrow
    const unsigned short* b_base = ua_t + (size_t)lquad * (H * 8) + (wave * 128 + lrow) * 8;

    // ---- prologue: A(0),A(1),B(0) issued; pack A(0); barrier ----
    f32x4 fa[2][2];
    fa[0][0] = *(const f32x4*)(a_src);
    fa[0][1] = *(const f32x4*)(a_src + 4);
    fa[1][0] = *(const f32x4*)(a_src + 32);
    fa[1][1] = *(const f32x4*)(a_src + 36);
    bf16x8 bb[2][8];
    #pragma unroll
    for (int nt = 0; nt < 8; ++nt)
        bb[0][nt] = *(const bf16x8*)(b_base + nt * 128);

    {   // pack A(0): compiler waits only on fa[0] loads (counted vmcnt)
        uint4 w;
        w.x = pack_trunc(fa[0][0][0], fa[0][0][1]);
        w.y = pack_trunc(fa[0][0][2], fa[0][0][3]);
        w.z = pack_trunc(fa[0][1][0], fa[0][1][1]);
        w.w = pack_trunc(fa[0][1][2], fa[0][1][3]);
        *(uint4*)(alds + aoff(sq, srow)) = w;
    }

    f32x4 acc[4][8];
    #pragma unroll
    for (int mt = 0; mt < 4; ++mt)
        #pragma unroll
        for (int nt = 0; nt < 8; ++nt)
            acc[mt][nt] = (f32x4){0.f, 0.f, 0.f, 0.f};

    asm volatile("s_waitcnt lgkmcnt(0)" ::: "memory");
    __builtin_amdgcn_s_barrier();
    __builtin_amdgcn_sched_barrier(0);

    // ---- K-loop: 16 chunks of 32 k ----
    #pragma unroll
    for (int j = 0; j < 16; ++j) {
        // pack A(j+1) into its fresh LDS region (disjoint from chunk-j reads)
        if (j < 15) {
            f32x4 lo = fa[(j + 1) & 1][0], hi = fa[(j + 1) & 1][1];
            uint4 w;
            w.x = pack_trunc(lo[0], lo[1]);
            w.y = pack_trunc(lo[2], lo[3]);
            w.z = pack_trunc(hi[0], hi[1]);
            w.w = pack_trunc(hi[2], hi[3]);
            *(uint4*)(alds + aoff((j + 1) * 4 + sq, srow)) = w;
        }
        // issue A(j+2) into the buffer just freed by the pack
        if (j < 14) {
            fa[j & 1][0] = *(const f32x4*)(a_src + (j + 2) * 32);
            fa[j & 1][1] = *(const f32x4*)(a_src + (j + 2) * 32 + 4);
        }
        // issue B(j+1) (regs; retires whenever — no cross-thread visibility needed)
        if (j < 15) {
            #pragma unroll
            for (int nt = 0; nt < 8; ++nt)
                bb[(j + 1) & 1][nt] =
                    *(const bf16x8*)(b_base + (size_t)(j + 1) * 16384 + nt * 128);
        }

        __builtin_amdgcn_s_setprio(1);
        #pragma unroll
        for (int mt = 0; mt < 4; ++mt) {
            int k8 = j * 4 + lquad;
            bf16x8 af = *(const bf16x8*)(alds + aoff(k8, mt * 16 + lrow));
            #pragma unroll
            for (int nt = 0; nt < 8; ++nt)
                acc[mt][nt] = __builtin_amdgcn_mfma_f32_16x16x32_bf16(
                    af, bb[j & 1][nt], acc[mt][nt], 0, 0, 0);
        }
        __builtin_amdgcn_s_setprio(0);

        if (j < 15) {
            __builtin_amdgcn_sched_barrier(0);
            asm volatile("s_waitcnt lgkmcnt(0)" ::: "memory");  // A(j+1) writes visible
            __builtin_amdgcn_s_barrier();
            __builtin_amdgcn_sched_barrier(0);
        }
    }

    // ---- epilogue scalars (loaded late: frees 16 VGPR during K-loop) ----
    float va[8], qa[8];
    #pragma unroll
    for (int nt = 0; nt < 8; ++nt) {
        int n = wave * 128 + nt * 16 + lrow;
        va[nt] = va_w[n];
        qa[nt] = qadd[b * H + n];
    }

    // ---- score: row-sum over this wave's 128 n of tanh(kproj+qadd)*va ----
    #pragma unroll
    for (int mt = 0; mt < 4; ++mt) {
        #pragma unroll
        for (int r = 0; r < 4; ++r) {
            float s = 0.f;
            #pragma unroll
            for (int nt = 0; nt < 8; ++nt)
                s += tanh_fast(acc[mt][nt][r] + qa[nt]) * va[nt];
            s += __shfl_xor(s, 1); s += __shfl_xor(s, 2);
            s += __shfl_xor(s, 4); s += __shfl_xor(s, 8);
            if (lrow == 0) swave[wave][mt * 16 + lquad * 4 + r] = s;
        }
    }
    __syncthreads();

    // ---- p = exp(score/T) masked; per-block psum partial ----
    if (t < MT) {
        float score = (swave[0][t] + swave[1][t] + swave[2][t] + swave[3][t]
                     + va_b[0]) / temp[0];
        int l = m0 + t;
        float p = (l < valid[b]) ? __expf(score) : 0.f;
        p_out[(size_t)b * LK + l] = p;
        pbuf[t] = p;
        float s = p;
        s += __shfl_xor(s, 1);  s += __shfl_xor(s, 2);  s += __shfl_xor(s, 4);
        s += __shfl_xor(s, 8);  s += __shfl_xor(s, 16); s += __shfl_xor(s, 32);
        if (t == 0) psum_part[blk] = s;
    }
    __syncthreads();

    // ---- partial context: pc_part[blk][h] = sum_row p[row]*key_bf[row][h] ----
    {
        int oct = t & 63, rg = t >> 6;     // k-octet x row-group of 16
        float s8[8];
        #pragma unroll
        for (int jj = 0; jj < 8; ++jj) s8[jj] = 0.f;
        #pragma unroll
        for (int rr = 0; rr < 16; ++rr) {
            int row = rg * 16 + rr;
            bf16x8 kv = *(const bf16x8*)(alds + aoff(oct, row));
            float pr = pbuf[row];
            #pragma unroll
            for (int jj = 0; jj < 8; ++jj)
                s8[jj] += pr * (float)kv[jj];
        }
        #pragma unroll
        for (int jj = 0; jj < 8; ++jj)
            red[rg][oct * 8 + jj] = s8[jj];
    }
    __syncthreads();
    {
        #pragma unroll
        for (int rep = 0; rep < 2; ++rep) {
            int h = t + rep * 256;
            pc_part[(size_t)blk * H + h] = red[0][h] + red[1][h] + red[2][h] + red[3][h];
        }
    }
}

// ---- kernel 4: finalize ----
__global__ void finalize_kernel(const float* __restrict__ p, const float* __restrict__ pc_part,
                                const float* __restrict__ psum_part, float* __restrict__ out) {
    int b = blockIdx.x / 18;
    int seg = blockIdx.x % 18;
    int t = threadIdx.x;
    __shared__ float tmp;
    if (t < 64) {
        float v = psum_part[b * 64 + t];
        v += __shfl_xor(v, 1);  v += __shfl_xor(v, 2);  v += __shfl_xor(v, 4);
        v += __shfl_xor(v, 8);  v += __shfl_xor(v, 16); v += __shfl_xor(v, 32);
        if (t == 0) tmp = v;
    }
    __syncthreads();
    float inv = 1.0f / tmp;
    if (seg < 16) {
        int l = seg * 256 + t;
        out[B_SZ * H + (size_t)b * LK + l] = p[(size_t)b * LK + l] * inv;
    } else {
        int h = (seg - 16) * 256 + t;
        float s = 0.f;
        #pragma unroll 8
        for (int i = 0; i < 64; ++i)
            s += pc_part[((size_t)b * 64 + i) * H + h];
        out[b * H + h] = s * inv;
    }
}

extern "C" void kernel_launch(void* const* d_in, const int* in_sizes, int n_in,
                              void* d_out, int out_size, void* d_ws, size_t ws_size,
                              hipStream_t stream) {
    const float* query = (const float*)d_in[0];
    const float* keys  = (const float*)d_in[1];
    const float* Wa_w  = (const float*)d_in[2];
    const float* Wa_b  = (const float*)d_in[3];
    const float* Ua_w  = (const float*)d_in[4];
    const float* Ua_b  = (const float*)d_in[5];
    const float* Va_w  = (const float*)d_in[6];
    const float* Va_b  = (const float*)d_in[7];
    const float* temp  = (const float*)d_in[8];
    const int*   valid = (const int*)d_in[9];
    float* out = (float*)d_out;

    char* ws = (char*)d_ws;
    unsigned short* ua_t = (unsigned short*)ws;            //   524288 B
    float* qadd      = (float*)(ws + 524288);              //    65536 B
    float* p         = (float*)(ws + 589824);              //   524288 B
    float* psum_part = (float*)(ws + 1114112);             //     8192 B
    float* pc_part   = (float*)(ws + 1122304);             //  4194304 B

    cvt_ua_kernel<<<H, 256, 0, stream>>>(Ua_w, ua_t);
    qproj_kernel<<<B_SZ * 8, 256, 0, stream>>>(query, Wa_w, Wa_b, Ua_b, qadd);
    main_kernel<<<B_SZ * (LK / MT), 256, 0, stream>>>(keys, ua_t, qadd, Va_w, Va_b,
                                                      temp, valid, p, pc_part, psum_part);
    finalize_kernel<<<B_SZ * 18, 256, 0, stream>>>(p, pc_part, psum_part, out);
}